// Round 4
// baseline (104.226 us; speedup 1.0000x reference)
//
#include <hip/hip_runtime.h>
#include <math.h>

#define N_    1024
#define RANK_ 8
#define M_    8192

// Static device scratch (~1.3 MB), fully rewritten every call.
__device__ __align__(16) float  g_sp[RANK_ * M_];   // softplus(H)
__device__ __align__(16) float2 g_Y [RANK_ * M_];   // DFT stage-1 intermediate
__device__ __align__(16) float2 g_Hf[RANK_ * M_];   // FFT(softplus(H))
__device__ __align__(16) float  g_sw[N_ * RANK_];   // softmax(W, axis=1)

// sin/cos of 2*pi*rev
__device__ __forceinline__ void sc2pi(float rev, float& s, float& c) {
    const float TWO_PI = 6.2831853071795864769f;
    float a = TWO_PI * rev;
    s = __sinf(a);
    c = __cosf(a);
}

// ---------------- stage 0: softplus(H) ----------------
__global__ void k_softplus(const float* __restrict__ H) {
    int i = blockIdx.x * blockDim.x + threadIdx.x;
    if (i < RANK_ * M_) {
        float x = H[i];
        g_sp[i] = (x > 20.f) ? x : log1pf(expf(x));
    }
}

// ---------------- stage 0b: row softmax of W ----------------
__global__ void k_softmax(const float* __restrict__ W) {
    int n = blockIdx.x * blockDim.x + threadIdx.x;
    if (n < N_) {
        float v[RANK_];
        float mx = -1e30f;
#pragma unroll
        for (int r = 0; r < RANK_; ++r) { v[r] = W[n * RANK_ + r]; mx = fmaxf(mx, v[r]); }
        float s = 0.f;
#pragma unroll
        for (int r = 0; r < RANK_; ++r) { v[r] = expf(v[r] - mx); s += v[r]; }
        float inv = 1.f / s;
#pragma unroll
        for (int r = 0; r < RANK_; ++r) g_sw[n * RANK_ + r] = v[r] * inv;
    }
}

// ---------------- stage 1: Y[r][t1][k2] = sum_t2 sp[r][t1+64*t2] * W128^(k2*t2) ----------------
// 8192 = 64 (t1) * 128 (t2);  W128 = exp(-2i*pi/128)
__global__ void k_dft_stage1() {
    int tid = blockIdx.x * blockDim.x + threadIdx.x;   // 65536 threads
    if (tid >= RANK_ * M_) return;
    int k2 = tid & 127;
    int t1 = (tid >> 7) & 63;
    int r  = tid >> 13;
    const float* x = g_sp + r * M_ + t1;
    float ar = 0.f, ai = 0.f;
    for (int t2 = 0; t2 < 128; ++t2) {
        float xv = x[t2 * 64];
        int idx = (k2 * t2) & 127;           // exact angle index
        float rev = (float)idx * (1.0f / 128.0f);
        float s, c; sc2pi(rev, s, c);
        ar = fmaf(xv, c, ar);                // x * (c - i s)
        ai = fmaf(xv, -s, ai);
    }
    g_Y[tid] = make_float2(ar, ai);          // layout: r*8192 + t1*128 + k2 == tid
}

// ---------------- stage 2: Hf[r][k] = sum_t1 Y[r][t1][k&127] * W8192^(t1*k) ----------------
__global__ void k_dft_stage2() {
    int tid = blockIdx.x * blockDim.x + threadIdx.x;   // 65536 threads
    if (tid >= RANK_ * M_) return;
    int k = tid & 8191;
    int r = tid >> 13;
    int j = k & 127;
    const float2* y = g_Y + r * M_ + j;
    float ar = 0.f, ai = 0.f;
    for (int t1 = 0; t1 < 64; ++t1) {
        float2 yv = y[t1 * 128];
        int idx = (t1 * k) & 8191;           // exact angle index
        float rev = (float)idx * (1.0f / 8192.0f);
        float s, c; sc2pi(rev, s, c);
        // (yr + i*yi) * (c - i*s)
        ar += yv.x * c + yv.y * s;
        ai += yv.y * c - yv.x * s;
    }
    g_Hf[tid] = make_float2(ar, ai);
}

// ---------------- main: out[n,m] = Re(V[n,m]) = sum_r sw[n,r]*(cos*hr + sin*hi) ----------------
// angle = 2*pi*tau[n,r]*m/M, (hr,hi) = Hf[r,m].
// d_out is (N, M) float32 (out_size = N*M): the harness reads the complex64
// reference flattened to N*M float elements -> real part (see R3 post-mortem).
#define MT 4   // m-values per thread (float4 store)
#define NT 4   // n-rows per block (Hf loads amortized over NT rows)
__global__ __launch_bounds__(256) void k_main(const float* __restrict__ tau,
                                              float4* __restrict__ out,
                                              int out_size_floats) {
    int m0 = (blockIdx.x * 256 + threadIdx.x) * MT;
    int n0 = blockIdx.y * NT;
    const float invM = 1.0f / (float)M_;
    float f[MT];
#pragma unroll
    for (int j = 0; j < MT; ++j) f[j] = (float)(m0 + j) * invM;

    float4 acc[NT];
#pragma unroll
    for (int i = 0; i < NT; ++i) acc[i] = make_float4(0.f, 0.f, 0.f, 0.f);

#pragma unroll
    for (int r = 0; r < RANK_; ++r) {
        // Hf[r, m0..m0+3] : two float4 loads = (re0,im0,re1,im1),(re2,im2,re3,im3)
        float4 h01 = *reinterpret_cast<const float4*>(&g_Hf[r * M_ + m0]);
        float4 h23 = *reinterpret_cast<const float4*>(&g_Hf[r * M_ + m0 + 2]);
        float hr[MT] = {h01.x, h01.z, h23.x, h23.z};
        float hi[MT] = {h01.y, h01.w, h23.y, h23.w};
#pragma unroll
        for (int i = 0; i < NT; ++i) {
            float tv = tau [(n0 + i) * RANK_ + r];
            float wv = g_sw[(n0 + i) * RANK_ + r];
            float re[MT];
#pragma unroll
            for (int j = 0; j < MT; ++j) {
                float rev = tv * f[j];
                rev -= floorf(rev);
                float s, c; sc2pi(rev, s, c);
                // Re(omega * Hf) with omega = c - i*s:  c*hr + s*hi
                re[j] = fmaf(c, hr[j], s * hi[j]);
            }
            acc[i].x = fmaf(wv, re[0], acc[i].x);
            acc[i].y = fmaf(wv, re[1], acc[i].y);
            acc[i].z = fmaf(wv, re[2], acc[i].z);
            acc[i].w = fmaf(wv, re[3], acc[i].w);
        }
    }
    int max_f4 = out_size_floats >> 2;       // guarded stores: no OOB ever
#pragma unroll
    for (int i = 0; i < NT; ++i) {
        int idx = ((n0 + i) * M_ + m0) >> 2;
        if (idx < max_f4) out[idx] = acc[i];
    }
}

extern "C" void kernel_launch(void* const* d_in, const int* in_sizes, int n_in,
                              void* d_out, int out_size, void* d_ws, size_t ws_size,
                              hipStream_t stream) {
    const float* W   = (const float*)d_in[0];   // (N, RANK)
    const float* H   = (const float*)d_in[1];   // (RANK, M)
    const float* tau = (const float*)d_in[2];   // (N, RANK)

    float4* out = (float4*)d_out;

    k_softplus  <<<dim3((RANK_ * M_) / 256),      dim3(256), 0, stream>>>(H);
    k_softmax   <<<dim3((N_ + 255) / 256),        dim3(256), 0, stream>>>(W);
    k_dft_stage1<<<dim3((RANK_ * M_) / 256),      dim3(256), 0, stream>>>();
    k_dft_stage2<<<dim3((RANK_ * M_) / 256),      dim3(256), 0, stream>>>();
    k_main      <<<dim3(M_ / (256 * MT), N_ / NT), dim3(256), 0, stream>>>(tau, out, out_size);
}

// Round 5
// 94.503 us; speedup vs baseline: 1.1029x; 1.1029x over previous
//
#include <hip/hip_runtime.h>
#include <math.h>

#define N_    1024
#define RANK_ 8
#define M_    8192

// Static device scratch (~1.3 MB), fully rewritten every call.
__device__ __align__(16) float  g_sp [RANK_ * M_];  // softplus(H)
__device__ __align__(16) float2 g_Y  [RANK_ * M_];  // DFT stage-1 intermediate
__device__ __align__(16) float  g_Amp[RANK_ * M_];  // |FFT(softplus(H))|
__device__ __align__(16) float  g_Phi[RANK_ * M_];  // arg(FFT)/2pi  (revolutions)
__device__ __align__(16) float  g_sw [N_ * RANK_];  // softmax(W, axis=1)

// Raw HW trans ops: v_sin_f32 / v_cos_f32 compute sin/cos(S0 * 2pi) — input in
// REVOLUTIONS (cdna4_isa.md §3). Inputs must be range-reduced via fract.
__device__ __forceinline__ float cos2pi(float rev) { return __builtin_amdgcn_cosf(rev); }
__device__ __forceinline__ float sin2pi(float rev) { return __builtin_amdgcn_sinf(rev); }

// ---------------- stage 0: softplus(H) ----------------
__global__ void k_softplus(const float* __restrict__ H) {
    int i = blockIdx.x * blockDim.x + threadIdx.x;
    if (i < RANK_ * M_) {
        float x = H[i];
        g_sp[i] = (x > 20.f) ? x : log1pf(expf(x));
    }
}

// ---------------- stage 0b: row softmax of W ----------------
__global__ void k_softmax(const float* __restrict__ W) {
    int n = blockIdx.x * blockDim.x + threadIdx.x;
    if (n < N_) {
        float v[RANK_];
        float mx = -1e30f;
#pragma unroll
        for (int r = 0; r < RANK_; ++r) { v[r] = W[n * RANK_ + r]; mx = fmaxf(mx, v[r]); }
        float s = 0.f;
#pragma unroll
        for (int r = 0; r < RANK_; ++r) { v[r] = expf(v[r] - mx); s += v[r]; }
        float inv = 1.f / s;
#pragma unroll
        for (int r = 0; r < RANK_; ++r) g_sw[n * RANK_ + r] = v[r] * inv;
    }
}

// ---------------- stage 1: Y[r][t1][k2] = sum_t2 sp[r][t1+64*t2] * W128^(k2*t2) ----------------
// 8192 = 64 (t1) * 128 (t2). Only 128 distinct twiddles -> LDS table instead of
// per-iteration transcendentals (2 trans -> 2 ds_read_b32 per iter).
__global__ void k_dft_stage1() {
    __shared__ float cs[128], sn[128];
    int t = threadIdx.x;
    if (t < 128) {
        float rev = (float)t * (1.0f / 128.0f);
        cs[t] = cos2pi(rev);
        sn[t] = sin2pi(rev);
    }
    __syncthreads();
    int tid = blockIdx.x * 256 + t;                // 65536 threads
    int k2 = tid & 127;
    int t1 = (tid >> 7) & 63;
    int r  = tid >> 13;
    const float* x = g_sp + r * M_ + t1;           // wave-uniform pointer
    float ar = 0.f, ai = 0.f;
    for (int t2 = 0; t2 < 128; ++t2) {
        float xv = x[t2 * 64];
        int id = (k2 * t2) & 127;
        ar = fmaf(xv,  cs[id], ar);                // x * (c - i s)
        ai = fmaf(xv, -sn[id], ai);
    }
    g_Y[tid] = make_float2(ar, ai);                // layout: r*8192 + t1*128 + k2 == tid
}

// ---------------- stage 2: Hf[r][k] = sum_t1 Y[r][t1][k&127] * W8192^(t1*k) ----------------
// Epilogue converts to amplitude/phase: Hf = A * e^{i*2pi*phi}.
__global__ void k_dft_stage2() {
    int tid = blockIdx.x * blockDim.x + threadIdx.x;   // 65536 threads
    if (tid >= RANK_ * M_) return;
    int k = tid & 8191;
    int r = tid >> 13;
    int j = k & 127;
    const float2* y = g_Y + r * M_ + j;
    float ar = 0.f, ai = 0.f;
    for (int t1 = 0; t1 < 64; ++t1) {
        float2 yv = y[t1 * 128];
        int idx = (t1 * k) & 8191;                 // exact angle index, in [0,8192)
        float rev = (float)idx * (1.0f / 8192.0f); // already in [0,1)
        float s = sin2pi(rev), c = cos2pi(rev);
        // (yr + i*yi) * (c - i*s)
        ar += yv.x * c + yv.y * s;
        ai += yv.y * c - yv.x * s;
    }
    g_Amp[tid] = sqrtf(ar * ar + ai * ai);
    g_Phi[tid] = atan2f(ai, ar) * 0.15915494309189535f;  // /(2pi) -> revolutions
}

// ---------------- main: out[n,m] = Re(V[n,m]) = sum_r sw[n,r] * A[r,m] * cos(2pi*(tau*f - phi)) ----------------
// d_out is (N, M) float32 = real part of the complex reference (established R4).
// Inner op: 1 fma + 1 fract + 1 v_cos + 1 fma  (vs 8 VALU + 2 trans before).
#define MT 4   // m-values per thread (float4 store)
#define NT 4   // n-rows per block (Amp/Phi loads amortized over NT rows)
__global__ __launch_bounds__(256) void k_main(const float* __restrict__ tau,
                                              float4* __restrict__ out,
                                              int out_size_floats) {
    int m0 = (blockIdx.x * 256 + threadIdx.x) * MT;
    int n0 = blockIdx.y * NT;
    const float invM = 1.0f / (float)M_;
    float f[MT];
#pragma unroll
    for (int j = 0; j < MT; ++j) f[j] = (float)(m0 + j) * invM;

    float4 acc[NT];
#pragma unroll
    for (int i = 0; i < NT; ++i) acc[i] = make_float4(0.f, 0.f, 0.f, 0.f);

#pragma unroll
    for (int r = 0; r < RANK_; ++r) {
        float4 A = *reinterpret_cast<const float4*>(&g_Amp[r * M_ + m0]);
        float4 P = *reinterpret_cast<const float4*>(&g_Phi[r * M_ + m0]);
#pragma unroll
        for (int i = 0; i < NT; ++i) {
            float tv = tau [(n0 + i) * RANK_ + r];   // wave-uniform -> s_load
            float wv = g_sw[(n0 + i) * RANK_ + r];
            float wA0 = wv * A.x, wA1 = wv * A.y, wA2 = wv * A.z, wA3 = wv * A.w;
            float c0 = cos2pi(__builtin_amdgcn_fractf(fmaf(tv, f[0], -P.x)));
            float c1 = cos2pi(__builtin_amdgcn_fractf(fmaf(tv, f[1], -P.y)));
            float c2 = cos2pi(__builtin_amdgcn_fractf(fmaf(tv, f[2], -P.z)));
            float c3 = cos2pi(__builtin_amdgcn_fractf(fmaf(tv, f[3], -P.w)));
            acc[i].x = fmaf(wA0, c0, acc[i].x);
            acc[i].y = fmaf(wA1, c1, acc[i].y);
            acc[i].z = fmaf(wA2, c2, acc[i].z);
            acc[i].w = fmaf(wA3, c3, acc[i].w);
        }
    }
    int max_f4 = out_size_floats >> 2;               // guarded stores: no OOB ever
#pragma unroll
    for (int i = 0; i < NT; ++i) {
        int idx = ((n0 + i) * M_ + m0) >> 2;
        if (idx < max_f4) out[idx] = acc[i];
    }
}

extern "C" void kernel_launch(void* const* d_in, const int* in_sizes, int n_in,
                              void* d_out, int out_size, void* d_ws, size_t ws_size,
                              hipStream_t stream) {
    const float* W   = (const float*)d_in[0];   // (N, RANK)
    const float* H   = (const float*)d_in[1];   // (RANK, M)
    const float* tau = (const float*)d_in[2];   // (N, RANK)

    float4* out = (float4*)d_out;

    k_softplus  <<<dim3((RANK_ * M_) / 256),       dim3(256), 0, stream>>>(H);
    k_softmax   <<<dim3((N_ + 255) / 256),         dim3(256), 0, stream>>>(W);
    k_dft_stage1<<<dim3((RANK_ * M_) / 256),       dim3(256), 0, stream>>>();
    k_dft_stage2<<<dim3((RANK_ * M_) / 256),       dim3(256), 0, stream>>>();
    k_main      <<<dim3(M_ / (256 * MT), N_ / NT), dim3(256), 0, stream>>>(tau, out, out_size);
}

// Round 6
// 85.924 us; speedup vs baseline: 1.2130x; 1.0998x over previous
//
#include <hip/hip_runtime.h>
#include <math.h>

#define N_    1024
#define RANK_ 8
#define M_    8192

typedef float vf2 __attribute__((ext_vector_type(2)));

// Static device scratch (~1.1 MB), fully rewritten every call.
__device__ __align__(16) float2 g_Y  [RANK_ * M_];  // DFT stage-1 intermediate
__device__ __align__(16) float  g_Amp[RANK_ * M_];  // |FFT(softplus(H))|
__device__ __align__(16) float  g_Phi[RANK_ * M_];  // arg(FFT)/2pi  (revolutions)
__device__ __align__(16) float  g_sw [N_ * RANK_];  // softmax(W, axis=1)

// v_sin_f32 / v_cos_f32: input in REVOLUTIONS (cdna4_isa.md §3); reduce via fract.
__device__ __forceinline__ float cos2pi(float rev) { return __builtin_amdgcn_cosf(rev); }
__device__ __forceinline__ float sin2pi(float rev) { return __builtin_amdgcn_sinf(rev); }

// ============ kernel A: fused softplus -> stage-1 DFT (blocks 0..255) + softmax(W) (blocks 256..259) ============
// stage 1: Y[r][t1][k2] = sum_t2 softplus(H)[r][t1+64*t2] * W128^(k2*t2),  8192 = 64(t1) x 128(t2)
// Block b<256 handles r = b>>5, t1 in {2(b&31), 2(b&31)+1}, all k2. Its 256 needed
// softplus values and the 128 distinct twiddles live in LDS.
__global__ __launch_bounds__(256) void k_pre(const float* __restrict__ H,
                                             const float* __restrict__ W) {
    if (blockIdx.x < 256) {
        __shared__ float spl[256];          // spl[h*128+j] = softplus(H[r, 2(b&31)+h + 64*j])
        __shared__ float cs[128], sn[128];  // twiddle table, 128 distinct angles
        int t    = threadIdx.x;
        int b    = blockIdx.x;
        int r    = b >> 5;
        int half = t >> 7;                  // wave-uniform (waves 0,1 -> 0; waves 2,3 -> 1)
        int j    = t & 127;
        int t1   = ((b & 31) << 1) | half;
        float x = H[r * M_ + t1 + (j << 6)];
        spl[half * 128 + j] = (x > 20.f) ? x : log1pf(expf(x));
        if (t < 128) {
            float rev = (float)t * (1.0f / 128.0f);
            cs[t] = cos2pi(rev);
            sn[t] = sin2pi(rev);
        }
        __syncthreads();
        int k2 = j;
        float ar = 0.f, ai = 0.f;
        for (int t2 = 0; t2 < 128; ++t2) {
            float xv = spl[half * 128 + t2];          // wave-uniform -> LDS broadcast
            int id = (k2 * t2) & 127;
            ar = fmaf(xv,  cs[id], ar);               // x * (c - i s)
            ai = fmaf(xv, -sn[id], ai);
        }
        g_Y[b * 256 + t] = make_float2(ar, ai);       // == g_Y[r*8192 + t1*128 + k2]
    } else {
        int n = (blockIdx.x - 256) * 256 + threadIdx.x;
        if (n < N_) {
            float v[RANK_];
            float mx = -1e30f;
#pragma unroll
            for (int r = 0; r < RANK_; ++r) { v[r] = W[n * RANK_ + r]; mx = fmaxf(mx, v[r]); }
            float s = 0.f;
#pragma unroll
            for (int r = 0; r < RANK_; ++r) { v[r] = expf(v[r] - mx); s += v[r]; }
            float inv = 1.f / s;
#pragma unroll
            for (int r = 0; r < RANK_; ++r) g_sw[n * RANK_ + r] = v[r] * inv;
        }
    }
}

// ============ kernel B: stage-2 DFT with rotation recurrence + amp/phase epilogue ============
// Hf[r][k] = sum_t1 Y[r][t1][k&127] * e^{-2pi*i*t1*k/8192}
// Twiddle angle increments by exactly k/8192 revolutions per t1 step -> rotate a
// unit rotor (4 fma) instead of 2 transcendentals per iteration.
__global__ void k_dft2() {
    int tid = blockIdx.x * blockDim.x + threadIdx.x;   // 65536 threads
    int k = tid & 8191;
    int r = tid >> 13;
    int j = k & 127;
    const float2* y = g_Y + r * M_ + j;
    float rev = (float)k * (1.0f / 8192.0f);           // exact in fp32
    float cr = cos2pi(rev), sr = sin2pi(rev);
    float c = 1.f, s = 0.f;                            // rotor at t1 = 0
    float ar = 0.f, ai = 0.f;
    for (int t1 = 0; t1 < 64; ++t1) {
        float2 yv = y[t1 * 128];                       // coalesced (lanes j-consecutive)
        // (yr + i*yi) * (c - i*s)
        ar = fmaf(yv.x, c, ar); ar = fmaf(yv.y, s, ar);
        ai = fmaf(yv.y, c, ai); ai = fmaf(-yv.x, s, ai);
        // angle += rev :  cos(a+b) = c*cr - s*sr ; sin(a+b) = s*cr + c*sr
        float cn = fmaf(c, cr, -(s * sr));
        float sn_ = fmaf(s, cr,  (c * sr));
        c = cn; s = sn_;
    }
    g_Amp[tid] = sqrtf(ar * ar + ai * ai);
    g_Phi[tid] = atan2f(ai, ar) * 0.15915494309189535f;  // /(2pi) -> revolutions
}

// ============ kernel C: out[n,m] = Re(V[n,m]) = sum_r sw[n,r] * A[r,m] * cos(2pi*(tau*f - phi)) ============
// d_out is (N, M) float32 = real part of the complex reference (established R4).
// vf2 math to encourage v_pk_fma_f32; 1 v_cos per element is the trans floor.
#define MT 4   // m-values per thread (float4 store)
#define NT 8   // n-rows per block (A/P L2 traffic halved vs NT=4)
__global__ __launch_bounds__(256) void k_main(const float* __restrict__ tau,
                                              float4* __restrict__ out,
                                              int out_size_floats) {
    int m0 = (blockIdx.x * 256 + threadIdx.x) * MT;
    int n0 = blockIdx.y * NT;
    const float invM = 1.0f / (float)M_;
    vf2 f01 = { (float)m0 * invM,       (float)(m0 + 1) * invM };
    vf2 f23 = { (float)(m0 + 2) * invM, (float)(m0 + 3) * invM };

    vf2 acc01[NT], acc23[NT];
#pragma unroll
    for (int i = 0; i < NT; ++i) { acc01[i] = (vf2){0.f, 0.f}; acc23[i] = (vf2){0.f, 0.f}; }

#pragma unroll
    for (int r = 0; r < RANK_; ++r) {
        float4 A = *reinterpret_cast<const float4*>(&g_Amp[r * M_ + m0]);
        float4 P = *reinterpret_cast<const float4*>(&g_Phi[r * M_ + m0]);
        vf2 A01 = {A.x, A.y}, A23 = {A.z, A.w};
        vf2 nP01 = {-P.x, -P.y}, nP23 = {-P.z, -P.w};
#pragma unroll
        for (int i = 0; i < NT; ++i) {
            float tv = tau [(n0 + i) * RANK_ + r];   // wave-uniform -> s_load
            float wv = g_sw[(n0 + i) * RANK_ + r];
            vf2 tvv  = {tv, tv};
            vf2 wvv  = {wv, wv};
            vf2 wA01 = wvv * A01;
            vf2 wA23 = wvv * A23;
            vf2 a01 = __builtin_elementwise_fma(tvv, f01, nP01);
            vf2 a23 = __builtin_elementwise_fma(tvv, f23, nP23);
            vf2 c01 = { cos2pi(__builtin_amdgcn_fractf(a01.x)),
                        cos2pi(__builtin_amdgcn_fractf(a01.y)) };
            vf2 c23 = { cos2pi(__builtin_amdgcn_fractf(a23.x)),
                        cos2pi(__builtin_amdgcn_fractf(a23.y)) };
            acc01[i] = __builtin_elementwise_fma(wA01, c01, acc01[i]);
            acc23[i] = __builtin_elementwise_fma(wA23, c23, acc23[i]);
        }
    }
    int max_f4 = out_size_floats >> 2;               // guarded stores: no OOB ever
#pragma unroll
    for (int i = 0; i < NT; ++i) {
        int idx = ((n0 + i) * M_ + m0) >> 2;
        if (idx < max_f4) {
            float4 o = { acc01[i].x, acc01[i].y, acc23[i].x, acc23[i].y };
            out[idx] = o;
        }
    }
}

extern "C" void kernel_launch(void* const* d_in, const int* in_sizes, int n_in,
                              void* d_out, int out_size, void* d_ws, size_t ws_size,
                              hipStream_t stream) {
    const float* W   = (const float*)d_in[0];   // (N, RANK)
    const float* H   = (const float*)d_in[1];   // (RANK, M)
    const float* tau = (const float*)d_in[2];   // (N, RANK)

    float4* out = (float4*)d_out;

    k_pre  <<<dim3(256 + N_ / 256),              dim3(256), 0, stream>>>(H, W);
    k_dft2 <<<dim3((RANK_ * M_) / 256),          dim3(256), 0, stream>>>();
    k_main <<<dim3(M_ / (256 * MT), N_ / NT),    dim3(256), 0, stream>>>(tau, out, out_size);
}